// Round 1
// baseline (1035.452 us; speedup 1.0000x reference)
//
#include <hip/hip_runtime.h>

// ---------------------------------------------------------------------------
// VectorQuantizerEMA: fp32 baseline
//   out0 z_q_st [N,D]  (== z_q numerically)
//   out1 indices [N] as float
//   out2 codebook_loss (scalar)  == out3 commitment_loss (scalar)
//   out4 embedding_new [K,D]
//   out5 ema_count_new [K]
//   out6 ema_weight_new [K,D]
// ---------------------------------------------------------------------------

#define DECAY 0.99f
#define OMD   0.01f
#define EPSC  1e-5f

constexpr int Dq = 256;
constexpr int Kn = 2048;
constexpr int Nq = 32768;

// ---------------- enorm: ||e_k||^2 -----------------------------------------
__global__ __launch_bounds__(256) void enorm_kernel(const float* __restrict__ emb,
                                                    float* __restrict__ enorm) {
    int k = blockIdx.x * 4 + (threadIdx.x >> 6);
    int lane = threadIdx.x & 63;
    const float4 v = *(const float4*)&emb[(size_t)k * Dq + lane * 4];
    float s = v.x * v.x + v.y * v.y + v.z * v.z + v.w * v.w;
#pragma unroll
    for (int o = 32; o > 0; o >>= 1) s += __shfl_down(s, o, 64);
    if (lane == 0) enorm[k] = s;
}

// ---------------- argmin + gather z_q + loss + histogram --------------------
// score = ||e||^2 - 2 x.e  (||x||^2 is per-query constant -> same argmin)
// Tile: 64 queries x 64 codes per block; D chunked by 128.
// LDS tiles are d-major with XOR-swizzled column groups:
//   phys col of logical col c at row r:  4*((c>>2) ^ ((r>>2)&15)) + (c&3)
__global__ __launch_bounds__(256, 2) void argmin_kernel(
    const float* __restrict__ x, const float* __restrict__ emb,
    const float* __restrict__ enorm, int* __restrict__ idx_out,
    float* __restrict__ idx_f_out, float* __restrict__ zq_out,
    int* __restrict__ counts, float* __restrict__ loss_acc)
{
    __shared__ float xs[128 * 64];   // 32 KiB
    __shared__ float es[128 * 64];   // 32 KiB
    const int tid = threadIdx.x;
    const int qg  = tid & 15;        // query group (4 queries each)
    const int kg  = tid >> 4;        // code group  (4 codes each)
    const int n0  = blockIdx.x * 64;

    const int dv = tid & 31;         // float4 index within 128-d chunk
    const int sw = dv & 15;          // swizzle for rows 4*dv .. 4*dv+3
    const int r0 = dv * 4;

    float bs[4];
    int   bi[4];
#pragma unroll
    for (int i = 0; i < 4; ++i) { bs[i] = 3.4e38f; bi[i] = 0; }

    for (int kt = 0; kt < Kn / 64; ++kt) {
        float acc[4][4];
#pragma unroll
        for (int i = 0; i < 4; ++i)
#pragma unroll
            for (int j = 0; j < 4; ++j) acc[i][j] = 0.f;

        for (int dc = 0; dc < 2; ++dc) {
            __syncthreads();   // protect LDS from previous compute readers
            // ---- stage x chunk (transposed + swizzled) ----
            {
                int q = tid >> 5;
#pragma unroll
                for (int it = 0; it < 8; ++it, q += 8) {
                    float4 v = *(const float4*)&x[(size_t)(n0 + q) * Dq + dc * 128 + dv * 4];
                    int col = ((q >> 2) ^ sw) * 4 + (q & 3);
                    xs[(r0 + 0) * 64 + col] = v.x;
                    xs[(r0 + 1) * 64 + col] = v.y;
                    xs[(r0 + 2) * 64 + col] = v.z;
                    xs[(r0 + 3) * 64 + col] = v.w;
                }
                int kk = tid >> 5;
#pragma unroll
                for (int it = 0; it < 8; ++it, kk += 8) {
                    float4 v = *(const float4*)&emb[(size_t)(kt * 64 + kk) * Dq + dc * 128 + dv * 4];
                    int col = ((kk >> 2) ^ sw) * 4 + (kk & 3);
                    es[(r0 + 0) * 64 + col] = v.x;
                    es[(r0 + 1) * 64 + col] = v.y;
                    es[(r0 + 2) * 64 + col] = v.z;
                    es[(r0 + 3) * 64 + col] = v.w;
                }
            }
            __syncthreads();
            // ---- compute 4x4 micro-tile over this d chunk ----
#pragma unroll 2
            for (int d4 = 0; d4 < 32; ++d4) {
                const int s = d4 & 15;
                const float* xr = &xs[d4 * 256 + ((qg ^ s) * 4)];
                const float* er = &es[d4 * 256 + ((kg ^ s) * 4)];
#pragma unroll
                for (int dd = 0; dd < 4; ++dd) {
                    float4 a = *(const float4*)&xr[dd * 64];
                    float4 b = *(const float4*)&er[dd * 64];
                    acc[0][0] += a.x * b.x; acc[0][1] += a.x * b.y;
                    acc[0][2] += a.x * b.z; acc[0][3] += a.x * b.w;
                    acc[1][0] += a.y * b.x; acc[1][1] += a.y * b.y;
                    acc[1][2] += a.y * b.z; acc[1][3] += a.y * b.w;
                    acc[2][0] += a.z * b.x; acc[2][1] += a.z * b.y;
                    acc[2][2] += a.z * b.z; acc[2][3] += a.z * b.w;
                    acc[3][0] += a.w * b.x; acc[3][1] += a.w * b.y;
                    acc[3][2] += a.w * b.z; acc[3][3] += a.w * b.w;
                }
            }
        }
        // ---- fold this k-tile into running best ----
#pragma unroll
        for (int j = 0; j < 4; ++j) {
            int k = kt * 64 + kg * 4 + j;
            float ee = enorm[k];
#pragma unroll
            for (int i = 0; i < 4; ++i) {
                float sc = ee - 2.f * acc[i][j];
                if (sc < bs[i]) { bs[i] = sc; bi[i] = k; }   // strict < keeps lowest k
            }
        }
    }

    // ---- cross-thread argmin reduction (16 kg groups per query) ----
    __syncthreads();
    float* rs = xs;           // [64][16] scores
    int*   ri = (int*)es;     // [64][16] indices
#pragma unroll
    for (int i = 0; i < 4; ++i) {
        int q = qg * 4 + i;
        rs[q * 16 + kg] = bs[i];
        ri[q * 16 + kg] = bi[i];
    }
    __syncthreads();
    if (tid < 64) {
        int q = tid;
        float best = rs[q * 16];
        int bidx = ri[q * 16];
        for (int j = 1; j < 16; ++j) {
            float s2 = rs[q * 16 + j];
            int id2 = ri[q * 16 + j];
            if (s2 < best || (s2 == best && id2 < bidx)) { best = s2; bidx = id2; }
        }
        idx_out[n0 + q] = bidx;
        idx_f_out[n0 + q] = (float)bidx;
        atomicAdd(&counts[bidx], 1);
        ((int*)xs)[1024 + q] = bidx;   // stash for gather phase
    }
    __syncthreads();

    // ---- gather z_q + squared-diff loss (4 threads per query) ----
    int gq = tid >> 2, part = tid & 3;
    int bk = ((int*)xs)[1024 + gq];
    const float4* ev = (const float4*)&emb[(size_t)bk * Dq + part * 64];
    const float4* xv = (const float4*)&x[(size_t)(n0 + gq) * Dq + part * 64];
    float4* ov = (float4*)&zq_out[(size_t)(n0 + gq) * Dq + part * 64];
    float lacc = 0.f;
#pragma unroll 4
    for (int t2 = 0; t2 < 16; ++t2) {
        float4 e4 = ev[t2];
        float4 x4 = xv[t2];
        ov[t2] = e4;
        float d0 = x4.x - e4.x, d1 = x4.y - e4.y;
        float d2 = x4.z - e4.z, d3 = x4.w - e4.w;
        lacc += d0 * d0 + d1 * d1 + d2 * d2 + d3 * d3;
    }
#pragma unroll
    for (int o = 32; o > 0; o >>= 1) lacc += __shfl_down(lacc, o, 64);
    if ((tid & 63) == 0) ((float*)es)[2048 + (tid >> 6)] = lacc;
    __syncthreads();
    if (tid == 0) {
        float t = ((float*)es)[2048] + ((float*)es)[2049] +
                  ((float*)es)[2050] + ((float*)es)[2051];
        atomicAdd(loss_acc, t);
    }
}

// ---------------- scan: offsets + smoothed counts ---------------------------
__global__ __launch_bounds__(256) void scan_kernel(
    const int* __restrict__ counts, const float* __restrict__ ema_count,
    int* __restrict__ offs, int* __restrict__ cursor,
    float* __restrict__ cnew, float* __restrict__ out_count)
{
    __shared__ int   si[256];
    __shared__ float sf[256];
    int t = threadIdx.x;
    int c[8], pre[8];
    int run = 0;
    float se = 0.f;
#pragma unroll
    for (int i = 0; i < 8; ++i) {
        c[i] = counts[t * 8 + i];
        pre[i] = run;
        run += c[i];
        se += ema_count[t * 8 + i];
    }
    si[t] = run;
    sf[t] = se;
    __syncthreads();
    for (int off = 1; off < 256; off <<= 1) {
        int v = (t >= off) ? si[t - off] : 0;
        __syncthreads();
        si[t] += v;
        __syncthreads();
    }
    int total_n = si[255];
    int base = si[t] - run;
    for (int off = 128; off > 0; off >>= 1) {
        if (t < off) sf[t] += sf[t + off];
        __syncthreads();
    }
    float total = DECAY * sf[0] + OMD * (float)total_n;
    float denom = total + 2048.0f * EPSC;
#pragma unroll
    for (int i = 0; i < 8; ++i) {
        int k = t * 8 + i;
        offs[k] = base + pre[i];
        cursor[k] = base + pre[i];
        float ck = DECAY * ema_count[k] + OMD * (float)c[i];
        float v = (ck + EPSC) / denom * total;
        cnew[k] = v;
        out_count[k] = v;
    }
}

// ---------------- fill: bucket queries by code ------------------------------
__global__ __launch_bounds__(256) void fill_kernel(const int* __restrict__ idx,
                                                   int* __restrict__ cursor,
                                                   int* __restrict__ sorted) {
    int n = blockIdx.x * 256 + threadIdx.x;
    int v = idx[n];
    int pos = atomicAdd(&cursor[v], 1);
    sorted[pos] = n;
}

// ---------------- per-code EMA weight update --------------------------------
__global__ __launch_bounds__(256) void weight_kernel(
    const float* __restrict__ x, const float* __restrict__ ema_weight,
    const int* __restrict__ counts, const int* __restrict__ offs,
    const int* __restrict__ sorted, const float* __restrict__ cnew,
    float* __restrict__ out_embed, float* __restrict__ out_weight)
{
    int k = blockIdx.x;
    int t = threadIdx.x;
    int cnt = counts[k];
    int base = offs[k];
    float acc = 0.f;
    for (int j = 0; j < cnt; ++j) {
        int n = sorted[base + j];
        acc += x[(size_t)n * Dq + t];
    }
    float w = DECAY * ema_weight[(size_t)k * Dq + t] + OMD * acc;
    out_weight[(size_t)k * Dq + t] = w;
    out_embed[(size_t)k * Dq + t] = w / cnew[k];
}

// ---------------- losses ----------------------------------------------------
__global__ void loss_kernel(const float* __restrict__ loss_acc,
                            float* __restrict__ out_cb, float* __restrict__ out_cm) {
    float v = loss_acc[0] / (float)((size_t)Nq * Dq);
    out_cb[0] = v;
    out_cm[0] = v;
}

// ---------------------------------------------------------------------------
extern "C" void kernel_launch(void* const* d_in, const int* in_sizes, int n_in,
                              void* d_out, int out_size, void* d_ws, size_t ws_size,
                              hipStream_t stream) {
    const float* z_e        = (const float*)d_in[0];
    const float* emb        = (const float*)d_in[1];
    const float* ema_count  = (const float*)d_in[2];
    const float* ema_weight = (const float*)d_in[3];

    float* out_zq     = (float*)d_out;
    float* out_idx    = out_zq + (size_t)Nq * Dq;
    float* out_cb     = out_idx + Nq;
    float* out_cm     = out_cb + 1;
    float* out_embed  = out_cm + 1;
    float* out_count  = out_embed + (size_t)Kn * Dq;
    float* out_weight = out_count + Kn;

    char* ws = (char*)d_ws;
    float* enorm    = (float*)(ws + 0);        // 2048 f
    int*   counts   = (int*)(ws + 8192);       // 2048 i
    int*   offs     = (int*)(ws + 16384);      // 2048 i
    int*   cursor   = (int*)(ws + 24576);      // 2048 i
    float* cnew     = (float*)(ws + 32768);    // 2048 f
    float* loss_acc = (float*)(ws + 40960);    // 1 f
    int*   idx      = (int*)(ws + 49152);      // 32768 i
    int*   sorted   = (int*)(ws + 49152 + 131072);

    hipMemsetAsync(counts, 0, Kn * sizeof(int), stream);
    hipMemsetAsync(loss_acc, 0, sizeof(float), stream);

    enorm_kernel<<<Kn / 4, 256, 0, stream>>>(emb, enorm);
    argmin_kernel<<<Nq / 64, 256, 0, stream>>>(z_e, emb, enorm, idx, out_idx,
                                               out_zq, counts, loss_acc);
    scan_kernel<<<1, 256, 0, stream>>>(counts, ema_count, offs, cursor, cnew, out_count);
    fill_kernel<<<Nq / 256, 256, 0, stream>>>(idx, cursor, sorted);
    weight_kernel<<<Kn, 256, 0, stream>>>(z_e, ema_weight, counts, offs, sorted,
                                          cnew, out_embed, out_weight);
    loss_kernel<<<1, 1, 0, stream>>>(loss_acc, out_cb, out_cm);
}

// Round 2
// 771.628 us; speedup vs baseline: 1.3419x; 1.3419x over previous
//
#include <hip/hip_runtime.h>

// ---------------------------------------------------------------------------
// VectorQuantizerEMA — round 2: fp32 argmin, 8x8 micro-tile, K-split=2
//   out0 z_q_st [N,D] | out1 indices [N] (float) | out2 codebook_loss
//   out3 commitment_loss | out4 embedding_new [K,D] | out5 ema_count_new [K]
//   out6 ema_weight_new [K,D]
// ---------------------------------------------------------------------------

#define DECAY 0.99f
#define OMD   0.01f
#define EPSC  1e-5f

constexpr int Dq = 256;
constexpr int Kn = 2048;
constexpr int Nq = 32768;

// ---------------- enorm: ||e_k||^2 -----------------------------------------
__global__ __launch_bounds__(256) void enorm_kernel(const float* __restrict__ emb,
                                                    float* __restrict__ enorm) {
    int k = blockIdx.x * 4 + (threadIdx.x >> 6);
    int lane = threadIdx.x & 63;
    const float4 v = *(const float4*)&emb[(size_t)k * Dq + lane * 4];
    float s = v.x * v.x + v.y * v.y + v.z * v.z + v.w * v.w;
#pragma unroll
    for (int o = 32; o > 0; o >>= 1) s += __shfl_down(s, o, 64);
    if (lane == 0) enorm[k] = s;
}

// ---------------- argmin phase A: per-split best ----------------------------
// grid 512: qtile = bx>>1 (128 queries), split = bx&1 (1024 codes).
// 256 threads: qg = tid>>4 (8 queries each), kg = tid&15 (8 codes each).
// LDS tiles d-major: xs[32 d][128 q], es[32 d][128 k]; 32 KiB total.
__device__ __forceinline__ void stage_load(const float4* __restrict__ x4,
                                           const float4* __restrict__ e4,
                                           int n0, int ks, int kt, int dc, int tid,
                                           float4 px[4], float4 pe[4]) {
    int c = tid & 7, nb = tid >> 3;
#pragma unroll
    for (int it = 0; it < 4; ++it) {
        int n = nb + 32 * it;
        px[it] = x4[(size_t)(n0 + n) * 64 + dc * 8 + c];
        pe[it] = e4[(size_t)(ks + kt * 128 + n) * 64 + dc * 8 + c];
    }
}

__global__ __launch_bounds__(256, 2) void argmin_kernel(
    const float* __restrict__ x, const float* __restrict__ emb,
    const float* __restrict__ enorm,
    float* __restrict__ wscore, int* __restrict__ widx)
{
    __shared__ float xs[32 * 128];   // 16 KiB
    __shared__ float es[32 * 128];   // 16 KiB
    const int tid = threadIdx.x;
    const int qg  = tid >> 4;
    const int kg  = tid & 15;
    const int n0  = (blockIdx.x >> 1) * 128;
    const int split = blockIdx.x & 1;
    const int ks  = split * 1024;

    const float4* x4 = (const float4*)x;
    const float4* e4 = (const float4*)emb;
    const int c = tid & 7, nb = tid >> 3;

    float bs[8];
    int   bi[8];
#pragma unroll
    for (int i = 0; i < 8; ++i) { bs[i] = 3.4e38f; bi[i] = 0; }

    float4 px[4], pe[4];
    stage_load(x4, e4, n0, ks, 0, 0, tid, px, pe);

    for (int kt = 0; kt < 8; ++kt) {
        float acc[8][8];
#pragma unroll
        for (int i = 0; i < 8; ++i)
#pragma unroll
            for (int j = 0; j < 8; ++j) acc[i][j] = 0.f;

        for (int dc = 0; dc < 8; ++dc) {
            __syncthreads();          // previous compute readers done
            // ---- write staged regs -> LDS (transposed, d-major) ----
#pragma unroll
            for (int it = 0; it < 4; ++it) {
                int n = nb + 32 * it;
                xs[(c * 4 + 0) * 128 + n] = px[it].x;
                xs[(c * 4 + 1) * 128 + n] = px[it].y;
                xs[(c * 4 + 2) * 128 + n] = px[it].z;
                xs[(c * 4 + 3) * 128 + n] = px[it].w;
                es[(c * 4 + 0) * 128 + n] = pe[it].x;
                es[(c * 4 + 1) * 128 + n] = pe[it].y;
                es[(c * 4 + 2) * 128 + n] = pe[it].z;
                es[(c * 4 + 3) * 128 + n] = pe[it].w;
            }
            __syncthreads();
            // ---- prefetch next chunk into regs (latency hidden by compute) ----
            int r = kt * 8 + dc + 1;
            if (r < 64) stage_load(x4, e4, n0, ks, r >> 3, r & 7, tid, px, pe);
            // ---- 8x8 micro-tile over 32 d's ----
            const float4* xa = ((const float4*)xs) + qg * 2;
            const float4* eb = ((const float4*)es) + kg * 2;
#pragma unroll 2
            for (int d = 0; d < 32; ++d) {
                float4 a0 = xa[d * 32], a1 = xa[d * 32 + 1];
                float4 b0 = eb[d * 32], b1 = eb[d * 32 + 1];
                float av[8] = {a0.x, a0.y, a0.z, a0.w, a1.x, a1.y, a1.z, a1.w};
                float bv[8] = {b0.x, b0.y, b0.z, b0.w, b1.x, b1.y, b1.z, b1.w};
#pragma unroll
                for (int i = 0; i < 8; ++i)
#pragma unroll
                    for (int j = 0; j < 8; ++j) acc[i][j] += av[i] * bv[j];
            }
        }
        // ---- fold ktile into running best (score = ||e||^2 - 2 x.e) ----
#pragma unroll
        for (int j = 0; j < 8; ++j) {
            int k = ks + kt * 128 + kg * 8 + j;
            float ee = enorm[k];
#pragma unroll
            for (int i = 0; i < 8; ++i) {
                float sc = ee - 2.f * acc[i][j];
                if (sc < bs[i]) { bs[i] = sc; bi[i] = k; }  // strict < keeps lowest k
            }
        }
    }

    // ---- cross-thread argmin (16 kg per query) via LDS ----
    __syncthreads();
    float* rs = xs;          // [128][16]
    int*   ri = (int*)es;    // [128][16]
#pragma unroll
    for (int i = 0; i < 8; ++i) {
        int q = qg * 8 + i;
        rs[q * 16 + kg] = bs[i];
        ri[q * 16 + kg] = bi[i];
    }
    __syncthreads();
    if (tid < 128) {
        int q = tid;
        float best = rs[q * 16];
        int bidx = ri[q * 16];
#pragma unroll
        for (int j = 1; j < 16; ++j) {
            float s2 = rs[q * 16 + j];
            int  id2 = ri[q * 16 + j];
            if (s2 < best || (s2 == best && id2 < bidx)) { best = s2; bidx = id2; }
        }
        wscore[split * Nq + n0 + q] = best;
        widx[split * Nq + n0 + q]  = bidx;
    }
}

// ---------------- merge: final argmin + gather z_q + loss + histogram -------
__global__ __launch_bounds__(256) void merge_kernel(
    const float* __restrict__ wscore, const int* __restrict__ widx,
    const float* __restrict__ x, const float* __restrict__ emb,
    int* __restrict__ idx_out, float* __restrict__ idx_f_out,
    float* __restrict__ zq_out, int* __restrict__ counts,
    float* __restrict__ loss_acc)
{
    __shared__ int sidx[64];
    __shared__ float lpart[4];
    const int tid = threadIdx.x;
    const int q0 = blockIdx.x * 64;

    if (tid < 64) {
        int q = q0 + tid;
        float s0 = wscore[q], s1 = wscore[Nq + q];
        int i0 = widx[q], i1 = widx[Nq + q];
        int b = (s1 < s0) ? i1 : i0;   // tie -> split 0 (lower indices)
        idx_out[q] = b;
        idx_f_out[q] = (float)b;
        atomicAdd(&counts[b], 1);
        sidx[tid] = b;
    }
    __syncthreads();

    int gq = tid >> 2, part = tid & 3;
    int bk = sidx[gq];
    const float4* ev = (const float4*)&emb[(size_t)bk * Dq + part * 64];
    const float4* xv = (const float4*)&x[(size_t)(q0 + gq) * Dq + part * 64];
    float4* ov = (float4*)&zq_out[(size_t)(q0 + gq) * Dq + part * 64];
    float lacc = 0.f;
#pragma unroll 4
    for (int t2 = 0; t2 < 16; ++t2) {
        float4 e4v = ev[t2];
        float4 x4v = xv[t2];
        ov[t2] = e4v;
        float d0 = x4v.x - e4v.x, d1 = x4v.y - e4v.y;
        float d2 = x4v.z - e4v.z, d3 = x4v.w - e4v.w;
        lacc += d0 * d0 + d1 * d1 + d2 * d2 + d3 * d3;
    }
#pragma unroll
    for (int o = 32; o > 0; o >>= 1) lacc += __shfl_down(lacc, o, 64);
    if ((tid & 63) == 0) lpart[tid >> 6] = lacc;
    __syncthreads();
    if (tid == 0)
        atomicAdd(loss_acc, lpart[0] + lpart[1] + lpart[2] + lpart[3]);
}

// ---------------- scan: offsets + smoothed counts + loss finalize -----------
__global__ __launch_bounds__(256) void scan_kernel(
    const int* __restrict__ counts, const float* __restrict__ ema_count,
    int* __restrict__ offs, int* __restrict__ cursor,
    float* __restrict__ cnew, float* __restrict__ out_count,
    const float* __restrict__ loss_acc, float* __restrict__ out_cb,
    float* __restrict__ out_cm)
{
    __shared__ int   si[256];
    __shared__ float sf[256];
    int t = threadIdx.x;
    int c[8], pre[8];
    int run = 0;
    float se = 0.f;
#pragma unroll
    for (int i = 0; i < 8; ++i) {
        c[i] = counts[t * 8 + i];
        pre[i] = run;
        run += c[i];
        se += ema_count[t * 8 + i];
    }
    si[t] = run;
    sf[t] = se;
    __syncthreads();
    for (int off = 1; off < 256; off <<= 1) {
        int v = (t >= off) ? si[t - off] : 0;
        __syncthreads();
        si[t] += v;
        __syncthreads();
    }
    int total_n = si[255];
    int base = si[t] - run;
    for (int off = 128; off > 0; off >>= 1) {
        if (t < off) sf[t] += sf[t + off];
        __syncthreads();
    }
    float total = DECAY * sf[0] + OMD * (float)total_n;
    float denom = total + 2048.0f * EPSC;
#pragma unroll
    for (int i = 0; i < 8; ++i) {
        int k = t * 8 + i;
        offs[k] = base + pre[i];
        cursor[k] = base + pre[i];
        float ck = DECAY * ema_count[k] + OMD * (float)c[i];
        float v = (ck + EPSC) / denom * total;
        cnew[k] = v;
        out_count[k] = v;
    }
    if (t == 0) {
        float v = loss_acc[0] / (float)((size_t)Nq * Dq);
        out_cb[0] = v;
        out_cm[0] = v;
    }
}

// ---------------- fill: bucket queries by code ------------------------------
__global__ __launch_bounds__(256) void fill_kernel(const int* __restrict__ idx,
                                                   int* __restrict__ cursor,
                                                   int* __restrict__ sorted) {
    int n = blockIdx.x * 256 + threadIdx.x;
    int v = idx[n];
    int pos = atomicAdd(&cursor[v], 1);
    sorted[pos] = n;
}

// ---------------- per-code EMA weight update --------------------------------
__global__ __launch_bounds__(256) void weight_kernel(
    const float* __restrict__ x, const float* __restrict__ ema_weight,
    const int* __restrict__ counts, const int* __restrict__ offs,
    const int* __restrict__ sorted, const float* __restrict__ cnew,
    float* __restrict__ out_embed, float* __restrict__ out_weight)
{
    int k = blockIdx.x;
    int t = threadIdx.x;
    int cnt = counts[k];
    int base = offs[k];
    float acc = 0.f;
    int j = 0;
    for (; j + 4 <= cnt; j += 4) {       // prefetch 4 indices, then 4 row loads
        int n0_ = sorted[base + j + 0];
        int n1_ = sorted[base + j + 1];
        int n2_ = sorted[base + j + 2];
        int n3_ = sorted[base + j + 3];
        float v0 = x[(size_t)n0_ * Dq + t];
        float v1 = x[(size_t)n1_ * Dq + t];
        float v2 = x[(size_t)n2_ * Dq + t];
        float v3 = x[(size_t)n3_ * Dq + t];
        acc += v0 + v1 + v2 + v3;
    }
    for (; j < cnt; ++j) {
        int n = sorted[base + j];
        acc += x[(size_t)n * Dq + t];
    }
    float w = DECAY * ema_weight[(size_t)k * Dq + t] + OMD * acc;
    out_weight[(size_t)k * Dq + t] = w;
    out_embed[(size_t)k * Dq + t] = w / cnew[k];
}

// ---------------------------------------------------------------------------
extern "C" void kernel_launch(void* const* d_in, const int* in_sizes, int n_in,
                              void* d_out, int out_size, void* d_ws, size_t ws_size,
                              hipStream_t stream) {
    const float* z_e        = (const float*)d_in[0];
    const float* emb        = (const float*)d_in[1];
    const float* ema_count  = (const float*)d_in[2];
    const float* ema_weight = (const float*)d_in[3];

    float* out_zq     = (float*)d_out;
    float* out_idx    = out_zq + (size_t)Nq * Dq;
    float* out_cb     = out_idx + Nq;
    float* out_cm     = out_cb + 1;
    float* out_embed  = out_cm + 1;
    float* out_count  = out_embed + (size_t)Kn * Dq;
    float* out_weight = out_count + Kn;

    char* ws = (char*)d_ws;
    float* enorm    = (float*)(ws + 0);         // 2048 f
    int*   counts   = (int*)(ws + 8192);        // 2048 i
    int*   offs     = (int*)(ws + 16384);       // 2048 i
    int*   cursor   = (int*)(ws + 24576);       // 2048 i
    float* cnew     = (float*)(ws + 32768);     // 2048 f
    float* loss_acc = (float*)(ws + 40960);     // 1 f
    int*   idx      = (int*)(ws + 49152);       // 32768 i
    int*   sorted   = (int*)(ws + 180224);      // 32768 i
    float* wscore   = (float*)(ws + 311296);    // 2*32768 f
    int*   widx     = (int*)(ws + 573440);      // 2*32768 i

    hipMemsetAsync(counts, 0, Kn * sizeof(int), stream);
    hipMemsetAsync(loss_acc, 0, sizeof(float), stream);

    enorm_kernel<<<Kn / 4, 256, 0, stream>>>(emb, enorm);
    argmin_kernel<<<512, 256, 0, stream>>>(z_e, emb, enorm, wscore, widx);
    merge_kernel<<<Nq / 64, 256, 0, stream>>>(wscore, widx, z_e, emb, idx,
                                              out_idx, out_zq, counts, loss_acc);
    scan_kernel<<<1, 256, 0, stream>>>(counts, ema_count, offs, cursor, cnew,
                                       out_count, loss_acc, out_cb, out_cm);
    fill_kernel<<<Nq / 256, 256, 0, stream>>>(idx, cursor, sorted);
    weight_kernel<<<Kn, 256, 0, stream>>>(z_e, ema_weight, counts, offs, sorted,
                                          cnew, out_embed, out_weight);
}

// Round 3
// 619.039 us; speedup vs baseline: 1.6727x; 1.2465x over previous
//
#include <hip/hip_runtime.h>

// ---------------------------------------------------------------------------
// VectorQuantizerEMA — round 3: bf16 hi/lo split MFMA argmin + exact rescue
// ---------------------------------------------------------------------------

#define DECAY 0.99f
#define OMD   0.01f
#define EPSC  1e-5f
#define MARGIN 0.025f

constexpr int Dq = 256;
constexpr int Kn = 2048;
constexpr int Nq = 32768;

typedef short bf16x8 __attribute__((ext_vector_type(8)));
typedef float f32x4 __attribute__((ext_vector_type(4)));

__device__ __forceinline__ unsigned short f2bf_rne(float f) {
    unsigned int u = __float_as_uint(f);
    unsigned int r = u + 0x7FFFu + ((u >> 16) & 1u);
    return (unsigned short)(r >> 16);
}
__device__ __forceinline__ float bf2f(unsigned short h) {
    return __uint_as_float(((unsigned int)h) << 16);
}
__device__ __forceinline__ void async_copy16(const void* g, void* l) {
    __builtin_amdgcn_global_load_lds(
        (const __attribute__((address_space(1))) unsigned int*)g,
        (__attribute__((address_space(3))) unsigned int*)l, 16, 0, 0);
}
__device__ __forceinline__ uint4 packbf(const unsigned short* h) {
    uint4 u;
    u.x = (unsigned)h[0] | ((unsigned)h[1] << 16);
    u.y = (unsigned)h[2] | ((unsigned)h[3] << 16);
    u.z = (unsigned)h[4] | ((unsigned)h[5] << 16);
    u.w = (unsigned)h[6] | ((unsigned)h[7] << 16);
    return u;
}

// ---------------- convert: fp32 -> frag-order bf16 hi/lo planes + enorm -----
// frag-order: granule(16B) for (row r, 32d-step ds, 8d-quad qd) at
//   ((r>>4)*8 + ds)*1024 + qd*256 + (r&15)*16
__global__ __launch_bounds__(256) void convert_kernel(
    const float* __restrict__ x, const float* __restrict__ emb,
    unsigned char* __restrict__ xh_g, unsigned char* __restrict__ xl_g,
    unsigned char* __restrict__ eh_g, unsigned char* __restrict__ el_g,
    float* __restrict__ enorm, int* __restrict__ counts,
    float* __restrict__ loss_acc, int* __restrict__ nflag)
{
    __shared__ float part[32][8];
    int b = blockIdx.x;
    bool is_e = (b >= 1024);
    const float* src = is_e ? emb : x;
    unsigned char* hg = is_e ? eh_g : xh_g;
    unsigned char* lg = is_e ? el_g : xl_g;
    int base_row = (is_e ? (b - 1024) : b) * 32;
    int t = threadIdx.x;
    if (b == 1024) {
        for (int i = t; i < Kn; i += 256) counts[i] = 0;
        if (t == 0) { loss_acc[0] = 0.f; nflag[0] = 0; }
    }
    int rg = t >> 7, ds = (t >> 4) & 7, rl = t & 15;
    int r = base_row + rg * 16 + rl;
    const float4* s4 = (const float4*)(src + (size_t)r * Dq + ds * 32);
    float v[32];
#pragma unroll
    for (int i = 0; i < 8; ++i) {
        float4 f = s4[i];
        v[i * 4 + 0] = f.x; v[i * 4 + 1] = f.y; v[i * 4 + 2] = f.z; v[i * 4 + 3] = f.w;
    }
    unsigned short hh[32], ll[32];
#pragma unroll
    for (int i = 0; i < 32; ++i) {
        hh[i] = f2bf_rne(v[i]);
        ll[i] = f2bf_rne(v[i] - bf2f(hh[i]));
    }
    size_t gb = ((size_t)(r >> 4) * 8 + ds) * 1024 + rl * 16;
#pragma unroll
    for (int qd = 0; qd < 4; ++qd) {
        *(uint4*)(hg + gb + qd * 256) = packbf(hh + qd * 8);
        *(uint4*)(lg + gb + qd * 256) = packbf(ll + qd * 8);
    }
    if (is_e) {
        float ps = 0.f;
#pragma unroll
        for (int i = 0; i < 32; ++i) ps += v[i] * v[i];
        part[rg * 16 + rl][ds] = ps;
        __syncthreads();
        if (t < 32) {
            float s = 0.f;
#pragma unroll
            for (int j = 0; j < 8; ++j) s += part[t][j];
            enorm[base_row + t] = s;
        }
    }
}

// ---------------- argmin: MFMA 3-term, 128q x 1024k per block (split=2) -----
// 4 waves in 2x2: wave covers 64q x 64k per k-tile(128). s1/s2/idx per lane.
__global__ __launch_bounds__(256, 2) void argmin_kernel(
    const unsigned char* __restrict__ xh_g, const unsigned char* __restrict__ xl_g,
    const unsigned char* __restrict__ eh_g, const unsigned char* __restrict__ el_g,
    const float* __restrict__ enorm,
    float* __restrict__ ws_s1, float* __restrict__ ws_s2, int* __restrict__ ws_k)
{
    __shared__ __align__(16) unsigned char lds[69632]; // 4x16KB tiles + 4KB enorm
    const int tid = threadIdx.x;
    const int lane = tid & 63, wave = tid >> 6;
    const int wq = wave >> 1, wk = wave & 1;
    const int rl = lane & 15, quad = lane >> 4;
    const int qb = blockIdx.x >> 1;         // 0..255 (128-query block)
    const int split = blockIdx.x & 1;

    // stage this split's enorm slice (1024 floats)
    ((float4*)(lds + 65536))[tid] = ((const float4*)(enorm + split * 1024))[tid];

    float s1[16], s2[16];
    int i1[16];
#pragma unroll
    for (int s = 0; s < 16; ++s) { s1[s] = 3.4e38f; s2[s] = 3.4e38f; i1[s] = 0; }

    const unsigned char* pg = (wave == 0) ? xh_g : (wave == 1) ? xl_g
                              : (wave == 2) ? eh_g : el_g;
    const int rb_x = qb * 8;

    for (int kt = 0; kt < 8; ++kt) {
        f32x4 acc[4][4];
#pragma unroll
        for (int mf = 0; mf < 4; ++mf)
#pragma unroll
            for (int nf = 0; nf < 4; ++nf) acc[mf][nf] = (f32x4){0.f, 0.f, 0.f, 0.f};

        const int rbase = (wave < 2) ? rb_x : (split * 64 + kt * 8);

        for (int ch = 0; ch < 4; ++ch) {
            __syncthreads();
            // each wave stages its plane: 16 granule-blocks of 1KB
#pragma unroll
            for (int i = 0; i < 16; ++i) {
                int mfb = i >> 1, ds = i & 1;
                size_t goff = ((size_t)(rbase + mfb) * 8 + ch * 2 + ds) * 1024
                              + (size_t)lane * 16;
                async_copy16(pg + goff, lds + wave * 16384 + i * 1024);
            }
            __syncthreads();
#pragma unroll
            for (int ds = 0; ds < 2; ++ds) {
                bf16x8 ah[4], al[4], bh[4], bl[4];
#pragma unroll
                for (int mf = 0; mf < 4; ++mf) {
                    int blk = ((wq * 4 + mf) * 2 + ds) * 1024 + lane * 16;
                    ah[mf] = *(const bf16x8*)(lds + blk);
                    al[mf] = *(const bf16x8*)(lds + 16384 + blk);
                }
#pragma unroll
                for (int nf = 0; nf < 4; ++nf) {
                    int blk = ((wk * 4 + nf) * 2 + ds) * 1024 + lane * 16;
                    bh[nf] = *(const bf16x8*)(lds + 32768 + blk);
                    bl[nf] = *(const bf16x8*)(lds + 49152 + blk);
                }
#pragma unroll
                for (int mf = 0; mf < 4; ++mf)
#pragma unroll
                    for (int nf = 0; nf < 4; ++nf) {
                        acc[mf][nf] = __builtin_amdgcn_mfma_f32_16x16x32_bf16(
                            ah[mf], bh[nf], acc[mf][nf], 0, 0, 0);
                        acc[mf][nf] = __builtin_amdgcn_mfma_f32_16x16x32_bf16(
                            ah[mf], bl[nf], acc[mf][nf], 0, 0, 0);
                        acc[mf][nf] = __builtin_amdgcn_mfma_f32_16x16x32_bf16(
                            al[mf], bh[nf], acc[mf][nf], 0, 0, 0);
                    }
            }
        }
        // fold: score = enorm - 2*dot ; keep (s1,i1) and s2
#pragma unroll
        for (int nf = 0; nf < 4; ++nf) {
            float ee = *(const float*)(lds + 65536 +
                         (kt * 128 + wk * 64 + nf * 16 + rl) * 4);
            int code = kt * 4 + nf;
#pragma unroll
            for (int mf = 0; mf < 4; ++mf)
#pragma unroll
                for (int r = 0; r < 4; ++r) {
                    int slot = mf * 4 + r;
                    float sc = fmaf(-2.f, acc[mf][nf][r], ee);
                    float worst = fmaxf(s1[slot], sc);
                    s2[slot] = fminf(s2[slot], worst);
                    bool lt = sc < s1[slot];
                    s1[slot] = lt ? sc : s1[slot];
                    i1[slot] = lt ? code : i1[slot];
                }
        }
    }

    // reconstruct full k, butterfly-reduce across the 16 rl lanes
    int kf[16];
#pragma unroll
    for (int s = 0; s < 16; ++s)
        kf[s] = split * 1024 + (i1[s] >> 2) * 128 + wk * 64 + (i1[s] & 3) * 16 + rl;
#pragma unroll
    for (int m = 1; m <= 8; m <<= 1) {
#pragma unroll
        for (int s = 0; s < 16; ++s) {
            float os1 = __shfl_xor(s1[s], m, 64);
            float os2 = __shfl_xor(s2[s], m, 64);
            int   ok  = __shfl_xor(kf[s], m, 64);
            float worst = fmaxf(s1[s], os1);
            s2[s] = fminf(fminf(s2[s], os2), worst);
            bool take = (os1 < s1[s]) || (os1 == s1[s] && ok < kf[s]);
            s1[s] = take ? os1 : s1[s];
            kf[s] = take ? ok : kf[s];
        }
    }
    __syncthreads();
    // per-q per-wk results into LDS, then merge the 2 k-half waves
    float* rs1 = (float*)lds;            // [128][2]
    float* rs2 = (float*)(lds + 1024);   // [128][2]
    int*   rk  = (int*)(lds + 2048);     // [128][2]
    if (rl == 0) {
#pragma unroll
        for (int s = 0; s < 16; ++s) {
            int ql = wq * 64 + (s >> 2) * 16 + quad * 4 + (s & 3);
            rs1[ql * 2 + wk] = s1[s];
            rs2[ql * 2 + wk] = s2[s];
            rk[ql * 2 + wk]  = kf[s];
        }
    }
    __syncthreads();
    if (tid < 128) {
        float a1 = rs1[tid * 2], b1 = rs1[tid * 2 + 1];
        float a2 = rs2[tid * 2], b2 = rs2[tid * 2 + 1];
        int ka = rk[tid * 2], kb = rk[tid * 2 + 1];
        bool take = (b1 < a1) || (b1 == a1 && kb < ka);
        float fs1 = take ? b1 : a1;
        int   fk  = take ? kb : ka;
        float fs2 = fminf(fminf(a2, b2), fmaxf(a1, b1));
        int q = qb * 128 + tid;
        ws_s1[split * Nq + q] = fs1;
        ws_s2[split * Nq + q] = fs2;
        ws_k[split * Nq + q]  = fk;
    }
}

// ---------------- pick: merge 2 splits, flag ambiguous queries --------------
__global__ __launch_bounds__(256) void pick_kernel(
    const float* __restrict__ ws_s1, const float* __restrict__ ws_s2,
    const int* __restrict__ ws_k, int* __restrict__ idx,
    int* __restrict__ nflag, int* __restrict__ flaglist)
{
    int q = blockIdx.x * 256 + threadIdx.x;
    float a1 = ws_s1[q], b1 = ws_s1[Nq + q];
    float a2 = ws_s2[q], b2 = ws_s2[Nq + q];
    int ka = ws_k[q], kb = ws_k[Nq + q];
    bool take = (b1 < a1) || (b1 == a1 && kb < ka);
    float s1 = take ? b1 : a1;
    int k = take ? kb : ka;
    float s2 = fminf(fminf(a2, b2), fmaxf(a1, b1));
    idx[q] = k;
    if (s2 - s1 < MARGIN) {
        int p = atomicAdd(nflag, 1);
        flaglist[p] = q;
    }
}

// ---------------- rescue: exact fp32 argmin for flagged queries -------------
__global__ __launch_bounds__(256) void rescue_kernel(
    const float* __restrict__ x, const float* __restrict__ emb,
    const float* __restrict__ enorm, const int* __restrict__ flaglist,
    const int* __restrict__ nflag, int* __restrict__ idx)
{
    __shared__ float xs[256];
    __shared__ float bsc[256];
    __shared__ int bix[256];
    int nf = nflag[0];
    int t = threadIdx.x;
    for (int it = blockIdx.x; it < nf; it += gridDim.x) {
        __syncthreads();
        int q = flaglist[it];
        xs[t] = x[(size_t)q * Dq + t];
        __syncthreads();
        float best = 3.4e38f;
        int bk = 0;
        for (int j = 0; j < 8; ++j) {
            int k = j * 256 + t;
            const float4* e4 = (const float4*)(emb + (size_t)k * Dq);
            const float4* x4 = (const float4*)xs;
            float d = 0.f;
#pragma unroll 8
            for (int c = 0; c < 64; ++c) {
                float4 e = e4[c], xv = x4[c];
                d = fmaf(e.x, xv.x, d); d = fmaf(e.y, xv.y, d);
                d = fmaf(e.z, xv.z, d); d = fmaf(e.w, xv.w, d);
            }
            float sc = enorm[k] - 2.f * d;
            if (sc < best || (sc == best && k < bk)) { best = sc; bk = k; }
        }
        bsc[t] = best; bix[t] = bk;
        __syncthreads();
        for (int o = 128; o > 0; o >>= 1) {
            if (t < o) {
                float so = bsc[t + o]; int io = bix[t + o];
                if (so < bsc[t] || (so == bsc[t] && io < bix[t])) {
                    bsc[t] = so; bix[t] = io;
                }
            }
            __syncthreads();
        }
        if (t == 0) idx[q] = bix[0];
    }
}

// ---------------- finalize: idx_f + histogram + gather z_q + loss -----------
__global__ __launch_bounds__(256) void finalize_kernel(
    const int* __restrict__ idx, const float* __restrict__ x,
    const float* __restrict__ emb, float* __restrict__ idx_f_out,
    float* __restrict__ zq_out, int* __restrict__ counts,
    float* __restrict__ loss_acc)
{
    __shared__ int sidx[64];
    __shared__ float lpart[4];
    const int tid = threadIdx.x;
    const int q0 = blockIdx.x * 64;
    if (tid < 64) {
        int b = idx[q0 + tid];
        idx_f_out[q0 + tid] = (float)b;
        atomicAdd(&counts[b], 1);
        sidx[tid] = b;
    }
    __syncthreads();
    int gq = tid >> 2, part = tid & 3;
    int bk = sidx[gq];
    const float4* ev = (const float4*)&emb[(size_t)bk * Dq + part * 64];
    const float4* xv = (const float4*)&x[(size_t)(q0 + gq) * Dq + part * 64];
    float4* ov = (float4*)&zq_out[(size_t)(q0 + gq) * Dq + part * 64];
    float lacc = 0.f;
#pragma unroll 4
    for (int t2 = 0; t2 < 16; ++t2) {
        float4 e4 = ev[t2];
        float4 x4 = xv[t2];
        ov[t2] = e4;
        float d0 = x4.x - e4.x, d1 = x4.y - e4.y;
        float d2 = x4.z - e4.z, d3 = x4.w - e4.w;
        lacc += d0 * d0 + d1 * d1 + d2 * d2 + d3 * d3;
    }
#pragma unroll
    for (int o = 32; o > 0; o >>= 1) lacc += __shfl_down(lacc, o, 64);
    if ((tid & 63) == 0) lpart[tid >> 6] = lacc;
    __syncthreads();
    if (tid == 0)
        atomicAdd(loss_acc, lpart[0] + lpart[1] + lpart[2] + lpart[3]);
}

// ---------------- scan: offsets + smoothed counts + loss outputs ------------
__global__ __launch_bounds__(256) void scan_kernel(
    const int* __restrict__ counts, const float* __restrict__ ema_count,
    int* __restrict__ offs, int* __restrict__ cursor,
    float* __restrict__ cnew, float* __restrict__ out_count,
    const float* __restrict__ loss_acc, float* __restrict__ out_cb,
    float* __restrict__ out_cm)
{
    __shared__ int   si[256];
    __shared__ float sf[256];
    int t = threadIdx.x;
    int c[8], pre[8];
    int run = 0;
    float se = 0.f;
#pragma unroll
    for (int i = 0; i < 8; ++i) {
        c[i] = counts[t * 8 + i];
        pre[i] = run;
        run += c[i];
        se += ema_count[t * 8 + i];
    }
    si[t] = run;
    sf[t] = se;
    __syncthreads();
    for (int off = 1; off < 256; off <<= 1) {
        int v = (t >= off) ? si[t - off] : 0;
        __syncthreads();
        si[t] += v;
        __syncthreads();
    }
    int total_n = si[255];
    int base = si[t] - run;
    for (int off = 128; off > 0; off >>= 1) {
        if (t < off) sf[t] += sf[t + off];
        __syncthreads();
    }
    float total = DECAY * sf[0] + OMD * (float)total_n;
    float denom = total + 2048.0f * EPSC;
#pragma unroll
    for (int i = 0; i < 8; ++i) {
        int k = t * 8 + i;
        offs[k] = base + pre[i];
        cursor[k] = base + pre[i];
        float ck = DECAY * ema_count[k] + OMD * (float)c[i];
        float v = (ck + EPSC) / denom * total;
        cnew[k] = v;
        out_count[k] = v;
    }
    if (t == 0) {
        float v = loss_acc[0] / (float)((size_t)Nq * Dq);
        out_cb[0] = v;
        out_cm[0] = v;
    }
}

// ---------------- fill: bucket queries by code ------------------------------
__global__ __launch_bounds__(256) void fill_kernel(const int* __restrict__ idx,
                                                   int* __restrict__ cursor,
                                                   int* __restrict__ sorted) {
    int n = blockIdx.x * 256 + threadIdx.x;
    int v = idx[n];
    int pos = atomicAdd(&cursor[v], 1);
    sorted[pos] = n;
}

// ---------------- per-code EMA weight update (4 codes/block, float4) --------
__global__ __launch_bounds__(256) void weight_kernel(
    const float* __restrict__ x, const float* __restrict__ ema_weight,
    const int* __restrict__ counts, const int* __restrict__ offs,
    const int* __restrict__ sorted, const float* __restrict__ cnew,
    float* __restrict__ out_embed, float* __restrict__ out_weight)
{
    int k = blockIdx.x * 4 + (threadIdx.x >> 6);
    int lane = threadIdx.x & 63;
    int cnt = counts[k];
    int base = offs[k];
    float4 acc = {0.f, 0.f, 0.f, 0.f};
    int j = 0;
    for (; j + 2 <= cnt; j += 2) {
        int n0 = sorted[base + j];
        int n1 = sorted[base + j + 1];
        float4 v0 = *(const float4*)(x + (size_t)n0 * Dq + lane * 4);
        float4 v1 = *(const float4*)(x + (size_t)n1 * Dq + lane * 4);
        acc.x += v0.x + v1.x; acc.y += v0.y + v1.y;
        acc.z += v0.z + v1.z; acc.w += v0.w + v1.w;
    }
    if (j < cnt) {
        int n = sorted[base + j];
        float4 v = *(const float4*)(x + (size_t)n * Dq + lane * 4);
        acc.x += v.x; acc.y += v.y; acc.z += v.z; acc.w += v.w;
    }
    float4 ew = *(const float4*)(ema_weight + (size_t)k * Dq + lane * 4);
    float inv = 1.f / cnew[k];
    float4 w;
    w.x = DECAY * ew.x + OMD * acc.x;
    w.y = DECAY * ew.y + OMD * acc.y;
    w.z = DECAY * ew.z + OMD * acc.z;
    w.w = DECAY * ew.w + OMD * acc.w;
    *(float4*)(out_weight + (size_t)k * Dq + lane * 4) = w;
    float4 e;
    e.x = w.x * inv; e.y = w.y * inv; e.z = w.z * inv; e.w = w.w * inv;
    *(float4*)(out_embed + (size_t)k * Dq + lane * 4) = e;
}

// ---------------------------------------------------------------------------
extern "C" void kernel_launch(void* const* d_in, const int* in_sizes, int n_in,
                              void* d_out, int out_size, void* d_ws, size_t ws_size,
                              hipStream_t stream) {
    const float* z_e        = (const float*)d_in[0];
    const float* emb        = (const float*)d_in[1];
    const float* ema_count  = (const float*)d_in[2];
    const float* ema_weight = (const float*)d_in[3];

    float* out_zq     = (float*)d_out;
    float* out_idx    = out_zq + (size_t)Nq * Dq;            // 8388608
    float* out_cb     = out_idx + Nq;                         // 8421376
    float* out_cm     = out_cb + 1;
    float* out_embed  = out_cm + 1;                           // 8421378
    float* out_count  = out_embed + (size_t)Kn * Dq;          // 8945666
    float* out_weight = out_count + Kn;                       // 8947714

    // scratch bf16 planes live inside d_out regions written later:
    unsigned char* xh_g = (unsigned char*)d_out;              // 16 MB (z_q area)
    unsigned char* xl_g = xh_g + 16777216;                    // 16 MB
    size_t eh_off = (((size_t)8421378 * 4) + 15) & ~(size_t)15;
    unsigned char* eh_g = (unsigned char*)d_out + eh_off;     // 1 MB (embed area)
    unsigned char* el_g = eh_g + 1048576;                     // 1 MB

    char* ws = (char*)d_ws;
    float* enorm    = (float*)(ws + 0);         // 2048 f
    int*   counts   = (int*)(ws + 8192);
    int*   offs     = (int*)(ws + 16384);
    int*   cursor   = (int*)(ws + 24576);
    float* cnew     = (float*)(ws + 32768);
    float* loss_acc = (float*)(ws + 40960);
    int*   nflag    = (int*)(ws + 40964);
    int*   idx      = (int*)(ws + 49152);       // 32768 i
    int*   sorted   = (int*)(ws + 180224);      // 32768 i
    int*   flaglist = (int*)(ws + 311296);      // 32768 i
    float* ws_s1    = (float*)(ws + 442368);    // 2*32768 f
    float* ws_s2    = (float*)(ws + 704512);    // 2*32768 f
    int*   ws_k     = (int*)(ws + 966656);      // 2*32768 i

    convert_kernel<<<1088, 256, 0, stream>>>(z_e, emb, xh_g, xl_g, eh_g, el_g,
                                             enorm, counts, loss_acc, nflag);
    argmin_kernel<<<512, 256, 0, stream>>>(xh_g, xl_g, eh_g, el_g, enorm,
                                           ws_s1, ws_s2, ws_k);
    pick_kernel<<<Nq / 256, 256, 0, stream>>>(ws_s1, ws_s2, ws_k, idx,
                                              nflag, flaglist);
    rescue_kernel<<<64, 256, 0, stream>>>(z_e, emb, enorm, flaglist, nflag, idx);
    finalize_kernel<<<Nq / 64, 256, 0, stream>>>(idx, z_e, emb, out_idx,
                                                 out_zq, counts, loss_acc);
    scan_kernel<<<1, 256, 0, stream>>>(counts, ema_count, offs, cursor, cnew,
                                       out_count, loss_acc, out_cb, out_cm);
    fill_kernel<<<Nq / 256, 256, 0, stream>>>(idx, cursor, sorted);
    weight_kernel<<<Kn / 4, 256, 0, stream>>>(z_e, ema_weight, counts, offs,
                                              sorted, cnew, out_embed, out_weight);
}

// Round 4
// 424.334 us; speedup vs baseline: 2.4402x; 1.4589x over previous
//
#include <hip/hip_runtime.h>

// ---------------------------------------------------------------------------
// VectorQuantizerEMA — round 4: fix weight-update load imbalance
//   (skewed code popularity -> worklist of <=32-row items + atomic accum)
// ---------------------------------------------------------------------------

#define DECAY 0.99f
#define OMD   0.01f
#define EPSC  1e-5f
#define MARGIN 0.025f

constexpr int Dq = 256;
constexpr int Kn = 2048;
constexpr int Nq = 32768;
constexpr int MAXITEMS = 3072;   // sum ceil(cnt/32) <= 2048 + 32768/32

typedef short bf16x8 __attribute__((ext_vector_type(8)));
typedef float f32x4 __attribute__((ext_vector_type(4)));

__device__ __forceinline__ unsigned short f2bf_rne(float f) {
    unsigned int u = __float_as_uint(f);
    unsigned int r = u + 0x7FFFu + ((u >> 16) & 1u);
    return (unsigned short)(r >> 16);
}
__device__ __forceinline__ float bf2f(unsigned short h) {
    return __uint_as_float(((unsigned int)h) << 16);
}
__device__ __forceinline__ void async_copy16(const void* g, void* l) {
    __builtin_amdgcn_global_load_lds(
        (const __attribute__((address_space(1))) unsigned int*)g,
        (__attribute__((address_space(3))) unsigned int*)l, 16, 0, 0);
}
__device__ __forceinline__ uint4 packbf(const unsigned short* h) {
    uint4 u;
    u.x = (unsigned)h[0] | ((unsigned)h[1] << 16);
    u.y = (unsigned)h[2] | ((unsigned)h[3] << 16);
    u.z = (unsigned)h[4] | ((unsigned)h[5] << 16);
    u.w = (unsigned)h[6] | ((unsigned)h[7] << 16);
    return u;
}

// ---------------- convert: fp32 -> frag-order bf16 hi/lo planes + enorm -----
__global__ __launch_bounds__(256) void convert_kernel(
    const float* __restrict__ x, const float* __restrict__ emb,
    unsigned char* __restrict__ xh_g, unsigned char* __restrict__ xl_g,
    unsigned char* __restrict__ eh_g, unsigned char* __restrict__ el_g,
    float* __restrict__ enorm, int* __restrict__ counts,
    float* __restrict__ loss_acc, int* __restrict__ nflag,
    int* __restrict__ nitems)
{
    __shared__ float part[32][8];
    int b = blockIdx.x;
    bool is_e = (b >= 1024);
    const float* src = is_e ? emb : x;
    unsigned char* hg = is_e ? eh_g : xh_g;
    unsigned char* lg = is_e ? el_g : xl_g;
    int base_row = (is_e ? (b - 1024) : b) * 32;
    int t = threadIdx.x;
    if (b == 1024) {
        for (int i = t; i < Kn; i += 256) counts[i] = 0;
        if (t == 0) { loss_acc[0] = 0.f; nflag[0] = 0; nitems[0] = 0; }
    }
    int rg = t >> 7, ds = (t >> 4) & 7, rl = t & 15;
    int r = base_row + rg * 16 + rl;
    const float4* s4 = (const float4*)(src + (size_t)r * Dq + ds * 32);
    float v[32];
#pragma unroll
    for (int i = 0; i < 8; ++i) {
        float4 f = s4[i];
        v[i * 4 + 0] = f.x; v[i * 4 + 1] = f.y; v[i * 4 + 2] = f.z; v[i * 4 + 3] = f.w;
    }
    unsigned short hh[32], ll[32];
#pragma unroll
    for (int i = 0; i < 32; ++i) {
        hh[i] = f2bf_rne(v[i]);
        ll[i] = f2bf_rne(v[i] - bf2f(hh[i]));
    }
    size_t gb = ((size_t)(r >> 4) * 8 + ds) * 1024 + rl * 16;
#pragma unroll
    for (int qd = 0; qd < 4; ++qd) {
        *(uint4*)(hg + gb + qd * 256) = packbf(hh + qd * 8);
        *(uint4*)(lg + gb + qd * 256) = packbf(ll + qd * 8);
    }
    if (is_e) {
        float ps = 0.f;
#pragma unroll
        for (int i = 0; i < 32; ++i) ps += v[i] * v[i];
        part[rg * 16 + rl][ds] = ps;
        __syncthreads();
        if (t < 32) {
            float s = 0.f;
#pragma unroll
            for (int j = 0; j < 8; ++j) s += part[t][j];
            enorm[base_row + t] = s;
        }
    }
}

// ---------------- argmin: MFMA 3-term, 128q x 1024k per block (split=2) -----
__global__ __launch_bounds__(256, 2) void argmin_kernel(
    const unsigned char* __restrict__ xh_g, const unsigned char* __restrict__ xl_g,
    const unsigned char* __restrict__ eh_g, const unsigned char* __restrict__ el_g,
    const float* __restrict__ enorm,
    float* __restrict__ ws_s1, float* __restrict__ ws_s2, int* __restrict__ ws_k)
{
    __shared__ __align__(16) unsigned char lds[69632];
    const int tid = threadIdx.x;
    const int lane = tid & 63, wave = tid >> 6;
    const int wq = wave >> 1, wk = wave & 1;
    const int rl = lane & 15, quad = lane >> 4;
    const int qb = blockIdx.x >> 1;
    const int split = blockIdx.x & 1;

    ((float4*)(lds + 65536))[tid] = ((const float4*)(enorm + split * 1024))[tid];

    float s1[16], s2[16];
    int i1[16];
#pragma unroll
    for (int s = 0; s < 16; ++s) { s1[s] = 3.4e38f; s2[s] = 3.4e38f; i1[s] = 0; }

    const unsigned char* pg = (wave == 0) ? xh_g : (wave == 1) ? xl_g
                              : (wave == 2) ? eh_g : el_g;
    const int rb_x = qb * 8;

    for (int kt = 0; kt < 8; ++kt) {
        f32x4 acc[4][4];
#pragma unroll
        for (int mf = 0; mf < 4; ++mf)
#pragma unroll
            for (int nf = 0; nf < 4; ++nf) acc[mf][nf] = (f32x4){0.f, 0.f, 0.f, 0.f};

        const int rbase = (wave < 2) ? rb_x : (split * 64 + kt * 8);

        for (int ch = 0; ch < 4; ++ch) {
            __syncthreads();
#pragma unroll
            for (int i = 0; i < 16; ++i) {
                int mfb = i >> 1, ds = i & 1;
                size_t goff = ((size_t)(rbase + mfb) * 8 + ch * 2 + ds) * 1024
                              + (size_t)lane * 16;
                async_copy16(pg + goff, lds + wave * 16384 + i * 1024);
            }
            __syncthreads();
#pragma unroll
            for (int ds = 0; ds < 2; ++ds) {
                bf16x8 ah[4], al[4], bh[4], bl[4];
#pragma unroll
                for (int mf = 0; mf < 4; ++mf) {
                    int blk = ((wq * 4 + mf) * 2 + ds) * 1024 + lane * 16;
                    ah[mf] = *(const bf16x8*)(lds + blk);
                    al[mf] = *(const bf16x8*)(lds + 16384 + blk);
                }
#pragma unroll
                for (int nf = 0; nf < 4; ++nf) {
                    int blk = ((wk * 4 + nf) * 2 + ds) * 1024 + lane * 16;
                    bh[nf] = *(const bf16x8*)(lds + 32768 + blk);
                    bl[nf] = *(const bf16x8*)(lds + 49152 + blk);
                }
#pragma unroll
                for (int mf = 0; mf < 4; ++mf)
#pragma unroll
                    for (int nf = 0; nf < 4; ++nf) {
                        acc[mf][nf] = __builtin_amdgcn_mfma_f32_16x16x32_bf16(
                            ah[mf], bh[nf], acc[mf][nf], 0, 0, 0);
                        acc[mf][nf] = __builtin_amdgcn_mfma_f32_16x16x32_bf16(
                            ah[mf], bl[nf], acc[mf][nf], 0, 0, 0);
                        acc[mf][nf] = __builtin_amdgcn_mfma_f32_16x16x32_bf16(
                            al[mf], bh[nf], acc[mf][nf], 0, 0, 0);
                    }
            }
        }
#pragma unroll
        for (int nf = 0; nf < 4; ++nf) {
            float ee = *(const float*)(lds + 65536 +
                         (kt * 128 + wk * 64 + nf * 16 + rl) * 4);
            int code = kt * 4 + nf;
#pragma unroll
            for (int mf = 0; mf < 4; ++mf)
#pragma unroll
                for (int r = 0; r < 4; ++r) {
                    int slot = mf * 4 + r;
                    float sc = fmaf(-2.f, acc[mf][nf][r], ee);
                    float worst = fmaxf(s1[slot], sc);
                    s2[slot] = fminf(s2[slot], worst);
                    bool lt = sc < s1[slot];
                    s1[slot] = lt ? sc : s1[slot];
                    i1[slot] = lt ? code : i1[slot];
                }
        }
    }

    int kf[16];
#pragma unroll
    for (int s = 0; s < 16; ++s)
        kf[s] = split * 1024 + (i1[s] >> 2) * 128 + wk * 64 + (i1[s] & 3) * 16 + rl;
#pragma unroll
    for (int m = 1; m <= 8; m <<= 1) {
#pragma unroll
        for (int s = 0; s < 16; ++s) {
            float os1 = __shfl_xor(s1[s], m, 64);
            float os2 = __shfl_xor(s2[s], m, 64);
            int   ok  = __shfl_xor(kf[s], m, 64);
            float worst = fmaxf(s1[s], os1);
            s2[s] = fminf(fminf(s2[s], os2), worst);
            bool take = (os1 < s1[s]) || (os1 == s1[s] && ok < kf[s]);
            s1[s] = take ? os1 : s1[s];
            kf[s] = take ? ok : kf[s];
        }
    }
    __syncthreads();
    float* rs1 = (float*)lds;
    float* rs2 = (float*)(lds + 1024);
    int*   rk  = (int*)(lds + 2048);
    if (rl == 0) {
#pragma unroll
        for (int s = 0; s < 16; ++s) {
            int ql = wq * 64 + (s >> 2) * 16 + quad * 4 + (s & 3);
            rs1[ql * 2 + wk] = s1[s];
            rs2[ql * 2 + wk] = s2[s];
            rk[ql * 2 + wk]  = kf[s];
        }
    }
    __syncthreads();
    if (tid < 128) {
        float a1 = rs1[tid * 2], b1 = rs1[tid * 2 + 1];
        float a2 = rs2[tid * 2], b2 = rs2[tid * 2 + 1];
        int ka = rk[tid * 2], kb = rk[tid * 2 + 1];
        bool take = (b1 < a1) || (b1 == a1 && kb < ka);
        float fs1 = take ? b1 : a1;
        int   fk  = take ? kb : ka;
        float fs2 = fminf(fminf(a2, b2), fmaxf(a1, b1));
        int q = qb * 128 + tid;
        ws_s1[split * Nq + q] = fs1;
        ws_s2[split * Nq + q] = fs2;
        ws_k[split * Nq + q]  = fk;
    }
}

// ---------------- pick: merge 2 splits, flag ambiguous queries --------------
__global__ __launch_bounds__(256) void pick_kernel(
    const float* __restrict__ ws_s1, const float* __restrict__ ws_s2,
    const int* __restrict__ ws_k, int* __restrict__ idx,
    int* __restrict__ nflag, int* __restrict__ flaglist)
{
    int q = blockIdx.x * 256 + threadIdx.x;
    float a1 = ws_s1[q], b1 = ws_s1[Nq + q];
    float a2 = ws_s2[q], b2 = ws_s2[Nq + q];
    int ka = ws_k[q], kb = ws_k[Nq + q];
    bool take = (b1 < a1) || (b1 == a1 && kb < ka);
    float s1 = take ? b1 : a1;
    int k = take ? kb : ka;
    float s2 = fminf(fminf(a2, b2), fmaxf(a1, b1));
    idx[q] = k;
    if (s2 - s1 < MARGIN) {
        int p = atomicAdd(nflag, 1);
        flaglist[p] = q;
    }
}

// ---------------- rescue: exact fp32 argmin for flagged queries -------------
__global__ __launch_bounds__(256) void rescue_kernel(
    const float* __restrict__ x, const float* __restrict__ emb,
    const float* __restrict__ enorm, const int* __restrict__ flaglist,
    const int* __restrict__ nflag, int* __restrict__ idx)
{
    __shared__ float xs[256];
    __shared__ float bsc[256];
    __shared__ int bix[256];
    int nf = nflag[0];
    int t = threadIdx.x;
    for (int it = blockIdx.x; it < nf; it += gridDim.x) {
        __syncthreads();
        int q = flaglist[it];
        xs[t] = x[(size_t)q * Dq + t];
        __syncthreads();
        float best = 3.4e38f;
        int bk = 0;
        for (int j = 0; j < 8; ++j) {
            int k = j * 256 + t;
            const float4* e4 = (const float4*)(emb + (size_t)k * Dq);
            const float4* x4 = (const float4*)xs;
            float d = 0.f;
#pragma unroll 8
            for (int c = 0; c < 64; ++c) {
                float4 e = e4[c], xv = x4[c];
                d = fmaf(e.x, xv.x, d); d = fmaf(e.y, xv.y, d);
                d = fmaf(e.z, xv.z, d); d = fmaf(e.w, xv.w, d);
            }
            float sc = enorm[k] - 2.f * d;
            if (sc < best || (sc == best && k < bk)) { best = sc; bk = k; }
        }
        bsc[t] = best; bix[t] = bk;
        __syncthreads();
        for (int o = 128; o > 0; o >>= 1) {
            if (t < o) {
                float so = bsc[t + o]; int io = bix[t + o];
                if (so < bsc[t] || (so == bsc[t] && io < bix[t])) {
                    bsc[t] = so; bix[t] = io;
                }
            }
            __syncthreads();
        }
        if (t == 0) idx[q] = bix[0];
    }
}

// ---------------- hist: histogram of final indices --------------------------
__global__ __launch_bounds__(256) void hist_kernel(const int* __restrict__ idx,
                                                   int* __restrict__ counts) {
    int q = blockIdx.x * 256 + threadIdx.x;
    atomicAdd(&counts[idx[q]], 1);
}

// ---------------- scan: offsets + smoothed counts + work items --------------
__global__ __launch_bounds__(256) void scan_kernel(
    const int* __restrict__ counts, const float* __restrict__ ema_count,
    int* __restrict__ offs, int* __restrict__ cursor,
    float* __restrict__ cnew, float* __restrict__ out_count,
    int* __restrict__ items, int* __restrict__ nitems)
{
    __shared__ int   si[256];
    __shared__ float sf[256];
    int t = threadIdx.x;
    int c[8], pre[8];
    int run = 0;
    float se = 0.f;
#pragma unroll
    for (int i = 0; i < 8; ++i) {
        c[i] = counts[t * 8 + i];
        pre[i] = run;
        run += c[i];
        se += ema_count[t * 8 + i];
    }
    si[t] = run;
    sf[t] = se;
    __syncthreads();
    for (int off = 1; off < 256; off <<= 1) {
        int v = (t >= off) ? si[t - off] : 0;
        __syncthreads();
        si[t] += v;
        __syncthreads();
    }
    int total_n = si[255];
    int base = si[t] - run;
    for (int off = 128; off > 0; off >>= 1) {
        if (t < off) sf[t] += sf[t + off];
        __syncthreads();
    }
    float total = DECAY * sf[0] + OMD * (float)total_n;
    float denom = total + 2048.0f * EPSC;
#pragma unroll
    for (int i = 0; i < 8; ++i) {
        int k = t * 8 + i;
        int o = base + pre[i];
        offs[k] = o;
        cursor[k] = o;
        float ck = DECAY * ema_count[k] + OMD * (float)c[i];
        float v = (ck + EPSC) / denom * total;
        cnew[k] = v;
        out_count[k] = v;
        if (c[i] > 0) {
            int nit = (c[i] + 31) >> 5;
            int ib = atomicAdd(nitems, nit);
            for (int j = 0; j < nit; ++j)
                items[ib + j] = (k << 17) | (o + j * 32);
        }
    }
}

// ---------------- fill: bucket queries by code ------------------------------
__global__ __launch_bounds__(256) void fill_kernel(const int* __restrict__ idx,
                                                   int* __restrict__ cursor,
                                                   int* __restrict__ sorted) {
    int n = blockIdx.x * 256 + threadIdx.x;
    int v = idx[n];
    int pos = atomicAdd(&cursor[v], 1);
    sorted[pos] = n;
}

// ---------------- weight_partial: <=32 rows per item, atomic accum ----------
__global__ __launch_bounds__(256) void weight_partial_kernel(
    const float* __restrict__ x, const int* __restrict__ sorted,
    const int* __restrict__ items, const int* __restrict__ nitems,
    const int* __restrict__ counts, const int* __restrict__ offs,
    float* __restrict__ accum)
{
    if ((int)blockIdx.x >= nitems[0]) return;
    int it = items[blockIdx.x];
    int k = it >> 17;
    int start = it & 0x1FFFF;
    int end = min(start + 32, offs[k] + counts[k]);
    int t = threadIdx.x;
    float acc = 0.f;
    int j = start;
    for (; j + 4 <= end; j += 4) {
        int n0 = sorted[j + 0], n1 = sorted[j + 1];
        int n2 = sorted[j + 2], n3 = sorted[j + 3];
        float v0 = x[(size_t)n0 * Dq + t];
        float v1 = x[(size_t)n1 * Dq + t];
        float v2 = x[(size_t)n2 * Dq + t];
        float v3 = x[(size_t)n3 * Dq + t];
        acc += v0 + v1 + v2 + v3;
    }
    for (; j < end; ++j) {
        int n = sorted[j];
        acc += x[(size_t)n * Dq + t];
    }
    atomicAdd(&accum[(size_t)k * Dq + t], acc);
}

// ---------------- weight_final: EMA + divide --------------------------------
__global__ __launch_bounds__(256) void weight_final_kernel(
    const float* __restrict__ accum, const float* __restrict__ ema_weight,
    const float* __restrict__ cnew,
    float* __restrict__ out_embed, float* __restrict__ out_weight)
{
    int gi = blockIdx.x * 256 + threadIdx.x;   // float4 index
    int k = gi >> 6;                           // 64 float4 per row
    float4 a = ((const float4*)accum)[gi];
    float4 ew = ((const float4*)ema_weight)[gi];
    float inv = 1.f / cnew[k];
    float4 w;
    w.x = DECAY * ew.x + OMD * a.x;
    w.y = DECAY * ew.y + OMD * a.y;
    w.z = DECAY * ew.z + OMD * a.z;
    w.w = DECAY * ew.w + OMD * a.w;
    ((float4*)out_weight)[gi] = w;
    float4 e;
    e.x = w.x * inv; e.y = w.y * inv; e.z = w.z * inv; e.w = w.w * inv;
    ((float4*)out_embed)[gi] = e;
}

// ---------------- finalize: idx_f + gather z_q + loss -----------------------
__global__ __launch_bounds__(256) void finalize_kernel(
    const int* __restrict__ idx, const float* __restrict__ x,
    const float* __restrict__ emb, float* __restrict__ idx_f_out,
    float* __restrict__ zq_out, float* __restrict__ loss_acc)
{
    __shared__ int sidx[64];
    __shared__ float lpart[4];
    const int tid = threadIdx.x;
    const int q0 = blockIdx.x * 64;
    if (tid < 64) {
        int b = idx[q0 + tid];
        idx_f_out[q0 + tid] = (float)b;
        sidx[tid] = b;
    }
    __syncthreads();
    int gq = tid >> 2, part = tid & 3;
    int bk = sidx[gq];
    const float4* ev = (const float4*)&emb[(size_t)bk * Dq + part * 64];
    const float4* xv = (const float4*)&x[(size_t)(q0 + gq) * Dq + part * 64];
    float4* ov = (float4*)&zq_out[(size_t)(q0 + gq) * Dq + part * 64];
    float lacc = 0.f;
#pragma unroll 4
    for (int t2 = 0; t2 < 16; ++t2) {
        float4 e4 = ev[t2];
        float4 x4 = xv[t2];
        ov[t2] = e4;
        float d0 = x4.x - e4.x, d1 = x4.y - e4.y;
        float d2 = x4.z - e4.z, d3 = x4.w - e4.w;
        lacc += d0 * d0 + d1 * d1 + d2 * d2 + d3 * d3;
    }
#pragma unroll
    for (int o = 32; o > 0; o >>= 1) lacc += __shfl_down(lacc, o, 64);
    if ((tid & 63) == 0) lpart[tid >> 6] = lacc;
    __syncthreads();
    if (tid == 0)
        atomicAdd(loss_acc, lpart[0] + lpart[1] + lpart[2] + lpart[3]);
}

// ---------------- loss_final ------------------------------------------------
__global__ void loss_final_kernel(const float* __restrict__ loss_acc,
                                  float* __restrict__ out_cb,
                                  float* __restrict__ out_cm) {
    float v = loss_acc[0] / (float)((size_t)Nq * Dq);
    out_cb[0] = v;
    out_cm[0] = v;
}

// ---------------------------------------------------------------------------
extern "C" void kernel_launch(void* const* d_in, const int* in_sizes, int n_in,
                              void* d_out, int out_size, void* d_ws, size_t ws_size,
                              hipStream_t stream) {
    const float* z_e        = (const float*)d_in[0];
    const float* emb        = (const float*)d_in[1];
    const float* ema_count  = (const float*)d_in[2];
    const float* ema_weight = (const float*)d_in[3];

    float* out_zq     = (float*)d_out;
    float* out_idx    = out_zq + (size_t)Nq * Dq;            // 8388608
    float* out_cb     = out_idx + Nq;
    float* out_cm     = out_cb + 1;
    float* out_embed  = out_cm + 1;                           // 8421378
    float* out_count  = out_embed + (size_t)Kn * Dq;
    float* out_weight = out_count + Kn;

    // scratch planes + accum live in d_out regions written later:
    unsigned char* xh_g = (unsigned char*)d_out;              // 16 MB (z_q area)
    unsigned char* xl_g = xh_g + 16777216;                    // 16 MB
    size_t eh_off = (((size_t)8421378 * 4) + 15) & ~(size_t)15;
    unsigned char* eh_g = (unsigned char*)d_out + eh_off;     // 1 MB (embed area)
    unsigned char* el_g = eh_g + 1048576;                     // 1 MB
    float* accum = (float*)d_out;                             // 2 MB, zeroed post-argmin

    char* ws = (char*)d_ws;
    float* enorm    = (float*)(ws + 0);
    int*   counts   = (int*)(ws + 8192);
    int*   offs     = (int*)(ws + 16384);
    int*   cursor   = (int*)(ws + 24576);
    float* cnew     = (float*)(ws + 32768);
    float* loss_acc = (float*)(ws + 40960);
    int*   nflag    = (int*)(ws + 40964);
    int*   nitems   = (int*)(ws + 40968);
    int*   idx      = (int*)(ws + 49152);       // 32768 i
    int*   sorted   = (int*)(ws + 180224);      // 32768 i
    int*   flaglist = (int*)(ws + 311296);      // 32768 i
    float* ws_s1    = (float*)(ws + 442368);    // 2*32768 f
    float* ws_s2    = (float*)(ws + 704512);    // 2*32768 f
    int*   ws_k     = (int*)(ws + 966656);      // 2*32768 i
    int*   items    = (int*)(ws + 1228800);     // 3072 i

    convert_kernel<<<1088, 256, 0, stream>>>(z_e, emb, xh_g, xl_g, eh_g, el_g,
                                             enorm, counts, loss_acc, nflag, nitems);
    argmin_kernel<<<512, 256, 0, stream>>>(xh_g, xl_g, eh_g, el_g, enorm,
                                           ws_s1, ws_s2, ws_k);
    hipMemsetAsync(accum, 0, (size_t)Kn * Dq * sizeof(float), stream);
    pick_kernel<<<Nq / 256, 256, 0, stream>>>(ws_s1, ws_s2, ws_k, idx,
                                              nflag, flaglist);
    rescue_kernel<<<64, 256, 0, stream>>>(z_e, emb, enorm, flaglist, nflag, idx);
    hist_kernel<<<Nq / 256, 256, 0, stream>>>(idx, counts);
    scan_kernel<<<1, 256, 0, stream>>>(counts, ema_count, offs, cursor, cnew,
                                       out_count, items, nitems);
    fill_kernel<<<Nq / 256, 256, 0, stream>>>(idx, cursor, sorted);
    weight_partial_kernel<<<MAXITEMS, 256, 0, stream>>>(z_e, sorted, items, nitems,
                                                        counts, offs, accum);
    weight_final_kernel<<<Kn * Dq / 1024, 256, 0, stream>>>(accum, ema_weight, cnew,
                                                            out_embed, out_weight);
    finalize_kernel<<<Nq / 64, 256, 0, stream>>>(idx, z_e, emb, out_idx,
                                                 out_zq, loss_acc);
    loss_final_kernel<<<1, 1, 0, stream>>>(loss_acc, out_cb, out_cm);
}